// Round 4
// baseline (356.187 us; speedup 1.0000x reference)
//
#include <hip/hip_runtime.h>
#include <math.h>

// Problem constants (from reference setup_inputs)
#define T_TOKENS 16384
#define DIM      2048
#define NEXP     64
#define TOPK     2

#define KB    1024            // K per block (grid splits K in 2: kc = blockIdx & 1)
#define BK    64              // K per LDS stage
#define NSTG  (KB / BK)       // 16 stages
#define XS    68              // padded LDS row stride (floats); 17*16B, bank-optimal

// Flat fp32 output layout: combine | topk_idx | gates | expert_activation
#define OFF_COMBINE 0
#define OFF_IDX     (T_TOKENS * NEXP)
#define OFF_GATES   (OFF_IDX + T_TOKENS * TOPK)
#define OFF_ACT     (OFF_GATES + T_TOKENS * TOPK)

__device__ __forceinline__ void fma8(float4& a0, float4& a1, float xs,
                                     const float* __restrict__ wr) {
    const float4 w0 = *reinterpret_cast<const float4*>(wr);
    const float4 w1 = *reinterpret_cast<const float4*>(wr + 4);
    a0.x = fmaf(xs, w0.x, a0.x); a0.y = fmaf(xs, w0.y, a0.y);
    a0.z = fmaf(xs, w0.z, a0.z); a0.w = fmaf(xs, w0.w, a0.w);
    a1.x = fmaf(xs, w1.x, a1.x); a1.y = fmaf(xs, w1.y, a1.y);
    a1.z = fmaf(xs, w1.z, a1.z); a1.w = fmaf(xs, w1.w, a1.w);
}

// K1: split-K GEMM. Grid = 512 blocks (tile = bx>>1, kc = bx&1) -> 2 blocks/CU,
// 8 waves/SIMD. 1024 threads = 16 waves = 8 expert-groups x 2 k-subranges.
// x is staged through LDS with COALESCED loads (4 segments/wave vs 64 for the
// old per-lane row stream); compute reads via bank-optimal ds_read_b128.
// w broadcasts via the scalar (s_load) path. acc = 8 fp32/lane.
__global__ __launch_bounds__(1024, 8)
void gemm_kernel(const float* __restrict__ x,
                 const float* __restrict__ w,     // [DIM][NEXP]
                 float* __restrict__ out,         // partial kc=0 -> combine region
                 float* __restrict__ p1) {        // partial kc=1 -> ws (4 MB)
    __shared__ float xsh[2][64][XS];    // 34.8 KB double-buffered x stage
    __shared__ float part[2][64][XS];   // 34.8 KB sub-K partials

    const int tid  = threadIdx.x;
    const int lane = tid & 63;
    const int wv   = __builtin_amdgcn_readfirstlane(tid >> 6);
    const int eg   = wv & 7;        // expert group: experts [eg*8, eg*8+8)
    const int sub  = wv >> 3;       // k-subrange within a stage (0/1)
    const int tile = blockIdx.x >> 1;
    const int kc   = blockIdx.x & 1;
    const int k0   = kc * KB;

    // Zero the expert-activation bins once (K1 completes before K2's atomics).
    if (blockIdx.x == 0 && tid < NEXP) out[OFF_ACT + tid] = 0.0f;

    // Coalesced staging pattern: thread -> (row sr, k-offset sc).
    const int sr = tid >> 4;
    const int sc = (tid & 15) * 4;
    const float* __restrict__ xg = x + (size_t)(tile * 64 + sr) * DIM + k0 + sc;

    float4 a0 = make_float4(0.f, 0.f, 0.f, 0.f);
    float4 a1 = a0;

    // Preload stage 0.
    *reinterpret_cast<float4*>(&xsh[0][sr][sc]) = *reinterpret_cast<const float4*>(xg);
    __syncthreads();

    const float* __restrict__ wp = w + (size_t)k0 * NEXP + eg * 8;

    #pragma unroll 1
    for (int s = 0; s < NSTG; ++s) {
        const int buf = s & 1;
        float4 nx = make_float4(0.f, 0.f, 0.f, 0.f);
        const bool more = (s + 1 < NSTG);
        if (more) nx = *reinterpret_cast<const float4*>(xg + (s + 1) * BK);

        const float* __restrict__ wr = wp + (size_t)(s * BK + sub * 32) * NEXP;
        #pragma unroll
        for (int kk = 0; kk < 32; kk += 4) {
            const float4 xv =
                *reinterpret_cast<const float4*>(&xsh[buf][lane][sub * 32 + kk]);
            fma8(a0, a1, xv.x, wr + (size_t)(kk + 0) * NEXP);
            fma8(a0, a1, xv.y, wr + (size_t)(kk + 1) * NEXP);
            fma8(a0, a1, xv.z, wr + (size_t)(kk + 2) * NEXP);
            fma8(a0, a1, xv.w, wr + (size_t)(kk + 3) * NEXP);
        }
        if (more) *reinterpret_cast<float4*>(&xsh[buf ^ 1][sr][sc]) = nx;
        __syncthreads();
    }

    // Combine the two k-subranges in LDS, then one coalesced 16 KB tile store.
    *reinterpret_cast<float4*>(&part[sub][lane][eg * 8])     = a0;
    *reinterpret_cast<float4*>(&part[sub][lane][eg * 8 + 4]) = a1;
    __syncthreads();
    {
        float4 pa       = *reinterpret_cast<const float4*>(&part[0][sr][sc]);
        const float4 pb = *reinterpret_cast<const float4*>(&part[1][sr][sc]);
        pa.x += pb.x; pa.y += pb.y; pa.z += pb.z; pa.w += pb.w;
        float* __restrict__ pd = kc ? p1 : (out + OFF_COMBINE);
        *reinterpret_cast<float4*>(pd + (size_t)(tile * 64 + sr) * NEXP + sc) = pa;
    }
}

// K2: logits = p0 + p1 + noise; top-2 + renormalized gates; all outputs.
// p0 lives in out's combine region and is overwritten (staged to LDS first).
__global__ __launch_bounds__(1024)
void finish_kernel(const float* __restrict__ p1,
                   const float* __restrict__ noise,
                   float* __restrict__ out) {
    __shared__ float lg[64][XS];
    __shared__ float g1s[64], g2s[64];
    __shared__ int   i1s[64], i2s[64];
    __shared__ float bins[NEXP];

    const int tid = threadIdx.x;
    const int r = tid >> 4, c = (tid & 15) * 4;
    const size_t rowbase = (size_t)(blockIdx.x * 64 + r) * NEXP + c;

    float4 a       = *reinterpret_cast<const float4*>(out + OFF_COMBINE + rowbase);
    const float4 b = *reinterpret_cast<const float4*>(p1 + rowbase);
    const float4 n = *reinterpret_cast<const float4*>(noise + rowbase);
    a.x += b.x + n.x; a.y += b.y + n.y; a.z += b.z + n.z; a.w += b.w + n.w;
    *reinterpret_cast<float4*>(&lg[r][c]) = a;
    if (tid < NEXP) bins[tid] = 0.0f;
    __syncthreads();

    if (tid < 64) {   // wave 0, lane = row
        const int rr = tid;
        float m1 = -1e30f, m2 = -1e30f;
        int i1 = 0, i2 = 0;
        #pragma unroll
        for (int j = 0; j < NEXP; j += 4) {
            const float4 s = *reinterpret_cast<const float4*>(&lg[rr][j]);
            if (s.x > m1) { m2 = m1; i2 = i1; m1 = s.x; i1 = j + 0; } else if (s.x > m2) { m2 = s.x; i2 = j + 0; }
            if (s.y > m1) { m2 = m1; i2 = i1; m1 = s.y; i1 = j + 1; } else if (s.y > m2) { m2 = s.y; i2 = j + 1; }
            if (s.z > m1) { m2 = m1; i2 = i1; m1 = s.z; i1 = j + 2; } else if (s.z > m2) { m2 = s.z; i2 = j + 2; }
            if (s.w > m1) { m2 = m1; i2 = i1; m1 = s.w; i1 = j + 3; } else if (s.w > m2) { m2 = s.w; i2 = j + 3; }
        }
        // Softmax Z cancels under top-2 renorm: g1 = 1/(1+exp(l2-l1)).
        const float t  = expf(m2 - m1);
        const float g1 = 1.0f / (1.0f + t);
        const float g2 = 1.0f - g1;

        const int row = blockIdx.x * 64 + rr;
        out[OFF_IDX + row * 2 + 0]   = (float)i1;
        out[OFF_IDX + row * 2 + 1]   = (float)i2;
        out[OFF_GATES + row * 2 + 0] = g1;
        out[OFF_GATES + row * 2 + 1] = g2;

        g1s[rr] = g1; g2s[rr] = g2; i1s[rr] = i1; i2s[rr] = i2;
        atomicAdd(&bins[i1], 1.0f);
        atomicAdd(&bins[i2], 1.0f);
    }
    __syncthreads();

    // Combine tile: coalesced float4 stores, overwriting the p0 region.
    {
        const int   ia = i1s[r], ib = i2s[r];
        const float ga = g1s[r], gb = g2s[r];
        float4 v;
        v.x = (c + 0 == ia) ? ga : (c + 0 == ib) ? gb : 0.0f;
        v.y = (c + 1 == ia) ? ga : (c + 1 == ib) ? gb : 0.0f;
        v.z = (c + 2 == ia) ? ga : (c + 2 == ib) ? gb : 0.0f;
        v.w = (c + 3 == ia) ? ga : (c + 3 == ib) ? gb : 0.0f;
        *reinterpret_cast<float4*>(out + OFF_COMBINE + rowbase) = v;
    }

    if (tid < NEXP) {
        const float v = bins[tid];
        if (v != 0.0f) atomicAdd(out + OFF_ACT + tid, v);
    }
}

extern "C" void kernel_launch(void* const* d_in, const int* in_sizes, int n_in,
                              void* d_out, int out_size, void* d_ws, size_t ws_size,
                              hipStream_t stream) {
    const float* x     = (const float*)d_in[0];
    const float* wg    = (const float*)d_in[1];
    const float* noise = (const float*)d_in[2];
    float* out = (float*)d_out;
    float* p1  = (float*)d_ws;   // needs 4 MB scratch for the kc=1 K-partial

    gemm_kernel<<<512, 1024, 0, stream>>>(x, wg, out, p1);
    finish_kernel<<<T_TOKENS / 64, 1024, 0, stream>>>(p1, noise, out);
}

// Round 5
// 254.597 us; speedup vs baseline: 1.3990x; 1.3990x over previous
//
#include <hip/hip_runtime.h>
#include <math.h>

// Problem constants (from reference setup_inputs)
#define T_TOKENS 16384
#define DIM      2048
#define NEXP     64
#define TOPK     2

#define KB    1024             // K per block (grid splits K in 2: kc = blockIdx & 1)
#define NKC   4                // K sub-chunks per block (one per wave group)
#define NEG   4                // expert groups per block
#define EPG   (NEXP / NEG)     // 16 experts per group
#define KC    (KB / NKC)       // 256 k's per wave
#define XS    68               // padded LDS row stride (floats)

// Flat fp32 output layout: combine | topk_idx | gates | expert_activation
#define OFF_COMBINE 0
#define OFF_IDX     (T_TOKENS * NEXP)
#define OFF_GATES   (OFF_IDX + T_TOKENS * TOPK)
#define OFF_ACT     (OFF_GATES + T_TOKENS * TOPK)

struct Acc { float4 a0, a1, a2, a3; };

__device__ __forceinline__ void fma16(Acc& A, float xs, const float* __restrict__ wr) {
    const float4 w0 = *reinterpret_cast<const float4*>(wr + 0);
    const float4 w1 = *reinterpret_cast<const float4*>(wr + 4);
    const float4 w2 = *reinterpret_cast<const float4*>(wr + 8);
    const float4 w3 = *reinterpret_cast<const float4*>(wr + 12);
    A.a0.x = fmaf(xs, w0.x, A.a0.x); A.a0.y = fmaf(xs, w0.y, A.a0.y);
    A.a0.z = fmaf(xs, w0.z, A.a0.z); A.a0.w = fmaf(xs, w0.w, A.a0.w);
    A.a1.x = fmaf(xs, w1.x, A.a1.x); A.a1.y = fmaf(xs, w1.y, A.a1.y);
    A.a1.z = fmaf(xs, w1.z, A.a1.z); A.a1.w = fmaf(xs, w1.w, A.a1.w);
    A.a2.x = fmaf(xs, w2.x, A.a2.x); A.a2.y = fmaf(xs, w2.y, A.a2.y);
    A.a2.z = fmaf(xs, w2.z, A.a2.z); A.a2.w = fmaf(xs, w2.w, A.a2.w);
    A.a3.x = fmaf(xs, w3.x, A.a3.x); A.a3.y = fmaf(xs, w3.y, A.a3.y);
    A.a3.z = fmaf(xs, w3.z, A.a3.z); A.a3.w = fmaf(xs, w3.w, A.a3.w);
}

__device__ __forceinline__ void fma16x4(Acc& A, float4 xv, const float* __restrict__ wr) {
    fma16(A, xv.x, wr);
    fma16(A, xv.y, wr + NEXP);
    fma16(A, xv.z, wr + 2 * NEXP);
    fma16(A, xv.w, wr + 3 * NEXP);
}

// K1: split-K GEMM, R3's proven inner loop (x divergent global + deep register
// pipeline on vmcnt; w on the scalar path) at 2 blocks/CU = 8 waves/SIMD.
// Grid 512: tile = bx>>1, kc = bx&1. 16 waves = 4 expert-groups x 4 k-chunks.
// lane = row; acc = 16 fp32/lane. No barriers inside the K-loop.
__global__ __launch_bounds__(1024, 8)
void gemm_kernel(const float* __restrict__ x,
                 const float* __restrict__ w,     // [DIM][NEXP]
                 float* __restrict__ out,         // kc=0 partial -> combine region
                 float* __restrict__ p1) {        // kc=1 partial -> ws (4 MB)
    __shared__ float part[NKC][64][XS];   // ~69.6 KB; 2 blocks/CU = 139 KB < 160 KB

    const int tid  = threadIdx.x;
    const int lane = tid & 63;
    const int wv   = __builtin_amdgcn_readfirstlane(tid >> 6);
    const int eg   = wv & (NEG - 1);      // expert group
    const int sub  = wv >> 2;             // k sub-chunk
    const int tile = blockIdx.x >> 1;
    const int kc   = blockIdx.x & 1;
    const int k0   = kc * KB + sub * KC;
    const int row  = tile * 64 + lane;

    if (blockIdx.x == 0 && tid < NEXP) out[OFF_ACT + tid] = 0.0f;

    Acc A;
    A.a0 = make_float4(0.f, 0.f, 0.f, 0.f);
    A.a1 = A.a0; A.a2 = A.a0; A.a3 = A.a0;

    const float* __restrict__ xp = x + (size_t)row * DIM + k0;
    const float* __restrict__ wp = w + (size_t)k0 * NEXP + eg * EPG;

    // Depth-2 pipeline over 16-k bodies: X=current, Y=next, Z=prefetch.
    float4 X0 = *reinterpret_cast<const float4*>(xp + 0);
    float4 X1 = *reinterpret_cast<const float4*>(xp + 4);
    float4 X2 = *reinterpret_cast<const float4*>(xp + 8);
    float4 X3 = *reinterpret_cast<const float4*>(xp + 12);
    float4 Y0 = *reinterpret_cast<const float4*>(xp + 16);
    float4 Y1 = *reinterpret_cast<const float4*>(xp + 20);
    float4 Y2 = *reinterpret_cast<const float4*>(xp + 24);
    float4 Y3 = *reinterpret_cast<const float4*>(xp + 28);

    #pragma unroll 1
    for (int kk = 0; kk < KC; kk += 16) {
        const int kpre = (kk + 32 < KC) ? (kk + 32) : 0;  // clamped prefetch
        const float4 Z0 = *reinterpret_cast<const float4*>(xp + kpre + 0);
        const float4 Z1 = *reinterpret_cast<const float4*>(xp + kpre + 4);
        const float4 Z2 = *reinterpret_cast<const float4*>(xp + kpre + 8);
        const float4 Z3 = *reinterpret_cast<const float4*>(xp + kpre + 12);

        const float* __restrict__ wr = wp + (size_t)kk * NEXP;
        fma16x4(A, X0, wr);
        fma16x4(A, X1, wr + 4 * NEXP);
        fma16x4(A, X2, wr + 8 * NEXP);
        fma16x4(A, X3, wr + 12 * NEXP);

        X0 = Y0; X1 = Y1; X2 = Y2; X3 = Y3;
        Y0 = Z0; Y1 = Z1; Y2 = Z2; Y3 = Z3;
    }

    // Reduce the 4 k-chunk partials in LDS, then one coalesced 16 KB store.
    {
        float* pr = &part[sub][lane][eg * EPG];
        *reinterpret_cast<float4*>(pr + 0)  = A.a0;
        *reinterpret_cast<float4*>(pr + 4)  = A.a1;
        *reinterpret_cast<float4*>(pr + 8)  = A.a2;
        *reinterpret_cast<float4*>(pr + 12) = A.a3;
    }
    __syncthreads();
    {
        const int sr = tid >> 4, sc = (tid & 15) * 4;
        float4 pa       = *reinterpret_cast<const float4*>(&part[0][sr][sc]);
        const float4 p1v = *reinterpret_cast<const float4*>(&part[1][sr][sc]);
        const float4 p2v = *reinterpret_cast<const float4*>(&part[2][sr][sc]);
        const float4 p3v = *reinterpret_cast<const float4*>(&part[3][sr][sc]);
        pa.x += p1v.x + p2v.x + p3v.x;
        pa.y += p1v.y + p2v.y + p3v.y;
        pa.z += p1v.z + p2v.z + p3v.z;
        pa.w += p1v.w + p2v.w + p3v.w;
        float* __restrict__ pd = kc ? p1 : (out + OFF_COMBINE);
        *reinterpret_cast<float4*>(pd + (size_t)(tile * 64 + sr) * NEXP + sc) = pa;
    }
}

// K2: logits = p0 + p1 + noise; top-2 + renormalized gates; all outputs.
// p0 lives in out's combine region and is overwritten (staged to LDS first).
__global__ __launch_bounds__(1024)
void finish_kernel(const float* __restrict__ p1,
                   const float* __restrict__ noise,
                   float* __restrict__ out) {
    __shared__ float lg[64][XS];
    __shared__ float g1s[64], g2s[64];
    __shared__ int   i1s[64], i2s[64];
    __shared__ float bins[NEXP];

    const int tid = threadIdx.x;
    const int r = tid >> 4, c = (tid & 15) * 4;
    const size_t rowbase = (size_t)(blockIdx.x * 64 + r) * NEXP + c;

    float4 a       = *reinterpret_cast<const float4*>(out + OFF_COMBINE + rowbase);
    const float4 b = *reinterpret_cast<const float4*>(p1 + rowbase);
    const float4 n = *reinterpret_cast<const float4*>(noise + rowbase);
    a.x += b.x + n.x; a.y += b.y + n.y; a.z += b.z + n.z; a.w += b.w + n.w;
    *reinterpret_cast<float4*>(&lg[r][c]) = a;
    if (tid < NEXP) bins[tid] = 0.0f;
    __syncthreads();

    if (tid < 64) {   // wave 0, lane = row
        const int rr = tid;
        float m1 = -1e30f, m2 = -1e30f;
        int i1 = 0, i2 = 0;
        #pragma unroll
        for (int j = 0; j < NEXP; j += 4) {
            const float4 s = *reinterpret_cast<const float4*>(&lg[rr][j]);
            if (s.x > m1) { m2 = m1; i2 = i1; m1 = s.x; i1 = j + 0; } else if (s.x > m2) { m2 = s.x; i2 = j + 0; }
            if (s.y > m1) { m2 = m1; i2 = i1; m1 = s.y; i1 = j + 1; } else if (s.y > m2) { m2 = s.y; i2 = j + 1; }
            if (s.z > m1) { m2 = m1; i2 = i1; m1 = s.z; i1 = j + 2; } else if (s.z > m2) { m2 = s.z; i2 = j + 2; }
            if (s.w > m1) { m2 = m1; i2 = i1; m1 = s.w; i1 = j + 3; } else if (s.w > m2) { m2 = s.w; i2 = j + 3; }
        }
        // Softmax Z cancels under top-2 renorm: g1 = 1/(1+exp(l2-l1)).
        const float t  = expf(m2 - m1);
        const float g1 = 1.0f / (1.0f + t);
        const float g2 = 1.0f - g1;

        const int row = blockIdx.x * 64 + rr;
        out[OFF_IDX + row * 2 + 0]   = (float)i1;
        out[OFF_IDX + row * 2 + 1]   = (float)i2;
        out[OFF_GATES + row * 2 + 0] = g1;
        out[OFF_GATES + row * 2 + 1] = g2;

        g1s[rr] = g1; g2s[rr] = g2; i1s[rr] = i1; i2s[rr] = i2;
        atomicAdd(&bins[i1], 1.0f);
        atomicAdd(&bins[i2], 1.0f);
    }
    __syncthreads();

    {
        const int   ia = i1s[r], ib = i2s[r];
        const float ga = g1s[r], gb = g2s[r];
        float4 v;
        v.x = (c + 0 == ia) ? ga : (c + 0 == ib) ? gb : 0.0f;
        v.y = (c + 1 == ia) ? ga : (c + 1 == ib) ? gb : 0.0f;
        v.z = (c + 2 == ia) ? ga : (c + 2 == ib) ? gb : 0.0f;
        v.w = (c + 3 == ia) ? ga : (c + 3 == ib) ? gb : 0.0f;
        *reinterpret_cast<float4*>(out + OFF_COMBINE + rowbase) = v;
    }

    if (tid < NEXP) {
        const float v = bins[tid];
        if (v != 0.0f) atomicAdd(out + OFF_ACT + tid, v);
    }
}

extern "C" void kernel_launch(void* const* d_in, const int* in_sizes, int n_in,
                              void* d_out, int out_size, void* d_ws, size_t ws_size,
                              hipStream_t stream) {
    const float* x     = (const float*)d_in[0];
    const float* wg    = (const float*)d_in[1];
    const float* noise = (const float*)d_in[2];
    float* out = (float*)d_out;
    float* p1  = (float*)d_ws;   // 4 MB scratch for the kc=1 K-partial

    gemm_kernel<<<512, 1024, 0, stream>>>(x, wg, out, p1);
    finish_kernel<<<T_TOKENS / 64, 1024, 0, stream>>>(p1, noise, out);
}